// Round 10
// baseline (215.610 us; speedup 1.0000x reference)
//
#include <hip/hip_runtime.h>
#include <math.h>

#define B_ 32
#define Q_ 1024
#define G_ 64
#define T_ 256    // build threads (4 waves); matcher runs on wave 0 only
#define K16 16    // columns per lane in matcher (Q_ / 64)
#define LROWS 32  // cost rows resident in LDS

// ---- cross-lane helpers -------------------------------------------------
template<int CTRL>
__device__ __forceinline__ int dpp_i32(int x) {
    return __builtin_amdgcn_update_dpp(x, x, CTRL, 0xF, 0xF, false);
}
template<int CTRL>
__device__ __forceinline__ double dpp_f64(double x) {
    union { double d; int i[2]; } a; a.d = x;
    union { int i[2]; double d; } r;
    r.i[0] = __builtin_amdgcn_update_dpp(a.i[0], a.i[0], CTRL, 0xF, 0xF, false);
    r.i[1] = __builtin_amdgcn_update_dpp(a.i[1], a.i[1], CTRL, 0xF, 0xF, false);
    return r.d;
}
#define ROR1 0x121
#define ROR2 0x122
#define ROR4 0x124
#define ROR8 0x128

__device__ __forceinline__ double readlane_f64(double x, int sl) {
    const int s = __builtin_amdgcn_readfirstlane(sl);
    union { double d; int i2[2]; } a; a.d = x;
    union { int i2[2]; double d; } r;
    r.i2[0] = __builtin_amdgcn_readlane(a.i2[0], s);
    r.i2[1] = __builtin_amdgcn_readlane(a.i2[1], s);
    return r.d;
}
__device__ __forceinline__ int readlane_i32(int x, int sl) {
    return __builtin_amdgcn_readlane(x, __builtin_amdgcn_readfirstlane(sl));
}
// uniform-index select from a 16-entry register array
__device__ __forceinline__ int sel16(const int* p, int s) {
    int v = p[0];
    #pragma unroll
    for (int k = 1; k < K16; ++k) v = (s == k) ? p[k] : v;
    return v;
}

// Fused: 256-thread cost build (rows<32 -> LDS; rows>=32 -> same-XCD ctg),
// then SINGLE-WAVE Jonker-Volgenant, software-pipelined:
//  - fast rows (sink on step 1) leave u,v unchanged => row cur+1's step-1
//    reduced costs r = (f64)c - v and argmin are INDEPENDENT of row cur.
//    Each iteration computes row cur+1's chain first, prefetches row cur+2,
//    then resolves row cur with last iteration's (minv, jm) — overlapping
//    consecutive rows' ~400-cycle argmin chains.
//  - slow path (rare): full Dijkstra, exact reference semantics; speculated
//    next-row result discarded and recomputed with the updated v.
template<bool HASWS>
__global__ __launch_bounds__(256, 1) void matcher_fused(
    const float* __restrict__ obj, const float* __restrict__ cd,
    const float* __restrict__ gi, const int* __restrict__ ngt,
    float* __restrict__ ctg, float* __restrict__ out_ind,
    float* __restrict__ out_mask)
{
    __shared__ float ldsct[LROWS * 1025];            // 2-way bank alias: free
    __shared__ int   row4col_[Q_];                   // hops + final output
    __shared__ __align__(16) char scratch_[LROWS * 65 * 4]; // tile (build) / sh dump

    float (*tile)[65] = (float (*)[65])scratch_;
    double* sh_lds    = (double*)scratch_;

    const int b = blockIdx.x;
    const int t = threadIdx.x;
    const int l = t & 63;
    const int w = t >> 6;
    const int g = ngt[b];

    const float* objb = obj + (b << 10);
    const float* cdb  = cd + ((size_t)b << 16);
    const float* gib  = gi + ((size_t)b << 16);
    float* ctgb = HASWS ? (ctg + ((size_t)b << 15)) : (float*)nullptr;

    for (int j = t; j < Q_; j += T_) row4col_[j] = -1;

    // ---- build: all 256 threads; rows<32 direct to LDS, rows>=32 via tile ----
    if (g > 0) {
        const float4* cd4 = (const float4*)cdb;
        const float4* gi4 = (const float4*)gib;
        for (int jb = 0; jb < Q_; jb += 64) {
            #pragma unroll
            for (int p = 0; p < 4; ++p) {
                const int f  = t + (p << 8);
                const int jj = f >> 4;          // 0..63
                const int q  = f & 15;          // i-quad
                const int i0 = q << 2;          // 0,4,..,60
                const int j  = jb + jj;
                const float om = __fmul_rn(5.0f, -objb[j]);
                const float4 c4 = cd4[(j << 4) + q];
                const float4 q4 = gi4[(j << 4) + q];
                const float r0 = __fadd_rn(__fadd_rn(om, __fmul_rn(10.0f, c4.x)), __fmul_rn(2.0f, -q4.x));
                const float r1 = __fadd_rn(__fadd_rn(om, __fmul_rn(10.0f, c4.y)), __fmul_rn(2.0f, -q4.y));
                const float r2 = __fadd_rn(__fadd_rn(om, __fmul_rn(10.0f, c4.z)), __fmul_rn(2.0f, -q4.z));
                const float r3 = __fadd_rn(__fadd_rn(om, __fmul_rn(10.0f, c4.w)), __fmul_rn(2.0f, -q4.w));
                if (i0 < LROWS) {
                    ldsct[(i0 + 0) * 1025 + j] = r0;
                    ldsct[(i0 + 1) * 1025 + j] = r1;
                    ldsct[(i0 + 2) * 1025 + j] = r2;
                    ldsct[(i0 + 3) * 1025 + j] = r3;
                } else if (HASWS) {
                    tile[i0 - LROWS + 0][jj] = r0;
                    tile[i0 - LROWS + 1][jj] = r1;
                    tile[i0 - LROWS + 2][jj] = r2;
                    tile[i0 - LROWS + 3][jj] = r3;
                }
            }
            __syncthreads();
            if (HASWS) {
                #pragma unroll
                for (int r = 0; r < 8; ++r) {   // 32 rows x 64 cols / 256 thr
                    const int idx = (r << 8) + t;
                    const int i2 = idx >> 6, j2 = idx & 63;
                    if (LROWS + i2 < g)
                        ctgb[(i2 << 10) + jb + j2] = tile[i2][j2];   // coalesced
                }
            }
            __syncthreads();
        }
    }

    // ---- matcher: wave 0 only, zero barriers in the hot loop ----
    if (w == 0 && g > 0) {
        float objm[K16];
        if (!HASWS) {
            #pragma unroll
            for (int k = 0; k < K16; ++k) objm[k] = __fmul_rn(5.0f, -objb[l + (k << 6)]);
        }
        auto load_row = [&](int i, float* c) {
            if (i < LROWS) {
                #pragma unroll
                for (int k = 0; k < K16; ++k) c[k] = ldsct[i * 1025 + l + (k << 6)];
            } else if (HASWS) {
                #pragma unroll
                for (int k = 0; k < K16; ++k) c[k] = ctgb[((i - LROWS) << 10) + l + (k << 6)];
            } else {
                #pragma unroll
                for (int k = 0; k < K16; ++k) {
                    const int j = l + (k << 6);
                    const int idx = (j << 6) + i;
                    c[k] = __fadd_rn(__fadd_rn(objm[k], __fmul_rn(10.0f, cdb[idx])),
                                     __fmul_rn(2.0f, -gib[idx]));
                }
            }
        };
        // argmin over cand[16]x64lanes: value via fmin tree/DPP, index via
        // eq-mask + ffs + min. Ties -> smallest j, exactly np.argmin.
        auto lexmin = [&](const double* cand, double& gv_o, int& jm_o) {
            double t8[8];
            #pragma unroll
            for (int m = 0; m < 8; ++m) t8[m] = fmin(cand[2 * m], cand[2 * m + 1]);
            double t4a = fmin(t8[0], t8[1]), t4b = fmin(t8[2], t8[3]);
            double t4c = fmin(t8[4], t8[5]), t4d = fmin(t8[6], t8[7]);
            double bv = fmin(fmin(t4a, t4b), fmin(t4c, t4d));
            bv = fmin(bv, dpp_f64<ROR1>(bv));
            bv = fmin(bv, dpp_f64<ROR2>(bv));
            bv = fmin(bv, dpp_f64<ROR4>(bv));
            bv = fmin(bv, dpp_f64<ROR8>(bv));
            const double g0 = readlane_f64(bv, 0),  g1 = readlane_f64(bv, 16);
            const double g2 = readlane_f64(bv, 32), g3 = readlane_f64(bv, 48);
            const double gv = fmin(fmin(g0, g1), fmin(g2, g3));
            unsigned msk = 0u;
            #pragma unroll
            for (int k = 0; k < K16; ++k) msk |= (cand[k] == gv) ? (1u << k) : 0u;
            int j = msk ? (((__ffs((int)msk) - 1) << 6) | l) : 0x7fffffff;
            { int o = dpp_i32<ROR1>(j); j = (o < j) ? o : j; }
            { int o = dpp_i32<ROR2>(j); j = (o < j) ? o : j; }
            { int o = dpp_i32<ROR4>(j); j = (o < j) ? o : j; }
            { int o = dpp_i32<ROR8>(j); j = (o < j) ? o : j; }
            int jm = __builtin_amdgcn_readlane(j, 0);
            const int j1 = __builtin_amdgcn_readlane(j, 16);
            const int j2 = __builtin_amdgcn_readlane(j, 32);
            const int j3 = __builtin_amdgcn_readlane(j, 48);
            jm = (j1 < jm) ? j1 : jm;
            jm = (j2 < jm) ? j2 : jm;
            jm = (j3 < jm) ? j3 : jm;
            gv_o = gv; jm_o = jm;
        };

        const double INF = __builtin_inf();
        double u_rep   = 0.0;     // u[l]
        int    c4r_rep = -1;      // col4row[l]
        unsigned asg   = 0u;      // bit k: column l+64k assigned
        double v_r[K16], sh_r[K16], r_cur[K16];
        int    path_r[K16];
        float  cN[K16], chop[K16];
        #pragma unroll
        for (int k = 0; k < K16; ++k) { v_r[k] = 0.0; path_r[k] = 0; }

        // ---- prime the pipeline: row 0's chain + row 1's costs ----
        double minv; int jm;
        {
            float c0[K16];
            load_row(0, c0);
            #pragma unroll
            for (int k = 0; k < K16; ++k) r_cur[k] = (double)c0[k] - v_r[k];
            lexmin(r_cur, minv, jm);
            if (g > 1) load_row(1, cN);
        }

        for (int cur = 0; cur < g; ++cur) {
            const bool hasnext = (cur + 1 < g);
            // 1. speculative next-row chain (independent of row cur on fast runs)
            double r_nx[K16], mv_n; int jm_n;
            if (hasnext) {
                #pragma unroll
                for (int k = 0; k < K16; ++k) r_nx[k] = (double)cN[k] - v_r[k];
                lexmin(r_nx, mv_n, jm_n);
            }
            // 2. prefetch row cur+2 (cN's old values already consumed)
            if (cur + 2 < g) load_row(cur + 2, cN);

            // 3. resolve row cur with (minv, jm) from the previous iteration
            const int owner0 = jm & 63, slot0 = jm >> 6;
            const unsigned oa0 = (unsigned)readlane_i32((int)asg, owner0);
            if (!((oa0 >> slot0) & 1u)) {
                // ---- fast row: O(1) state update (u,v unchanged for others) ----
                if (l == cur)    { u_rep += minv; c4r_rep = jm; }
                if (l == owner0) asg |= 1u << slot0;
                if (l == 0)      row4col_[jm] = cur;
            } else {
                // ---- slow path: materialize step-1 state, standard Dijkstra ----
                unsigned sc = 0u;
                #pragma unroll
                for (int k = 0; k < K16; ++k) { sh_r[k] = r_cur[k]; path_r[k] = cur; }
                if (l == owner0) sc |= 1u << slot0;
                int i = row4col_[jm];
                bool inSR = (l == cur) || (l == i);
                double ui = readlane_f64(u_rep, i);
                load_row(i, chop);
                int sink = -1;

                while (sink < 0) {
                    double cand[K16];
                    #pragma unroll
                    for (int k = 0; k < K16; ++k) {
                        const double rr = ((minv + (double)chop[k]) - ui) - v_r[k];
                        const bool notSC = !((sc >> k) & 1u);
                        const bool upd = notSC && (rr < sh_r[k]);   // strict <
                        sh_r[k]   = upd ? rr : sh_r[k];
                        path_r[k] = upd ? i : path_r[k];
                        cand[k] = notSC ? sh_r[k] : INF;
                    }
                    lexmin(cand, minv, jm);
                    if (l == (jm & 63)) sc |= 1u << (jm >> 6);
                    const unsigned oa = (unsigned)readlane_i32((int)asg, jm & 63);
                    if (!((oa >> (jm >> 6)) & 1u)) {
                        sink = jm;
                    } else {
                        i = row4col_[jm];
                        if (l == i) inSR = true;
                        ui = readlane_f64(u_rep, i);
                        load_row(i, chop);
                    }
                }

                // dual updates (reference order: u, then v, then augment)
                if (l == cur) u_rep += minv;
                #pragma unroll
                for (int k = 0; k < K16; ++k) sh_lds[l + (k << 6)] = sh_r[k];
                __builtin_amdgcn_wave_barrier();
                if (inSR && l != cur) u_rep += minv - sh_lds[c4r_rep];
                __builtin_amdgcn_wave_barrier();
                #pragma unroll
                for (int k = 0; k < K16; ++k) {
                    const double nv = v_r[k] - (minv - sh_r[k]);
                    v_r[k] = ((sc >> k) & 1u) ? nv : v_r[k];
                }

                // augment along alternating path
                int j = sink;
                while (true) {
                    const int so = j & 63, ss = j >> 6;
                    const int ii = readlane_i32(sel16(path_r, ss), so);
                    const int nj = readlane_i32(c4r_rep, ii);   // old col4row[ii]
                    if (l == 0) row4col_[j] = ii;
                    if (l == so) asg |= 1u << ss;
                    if (l == ii) c4r_rep = j;
                    j = nj;
                    if (ii == cur) break;
                }
                __builtin_amdgcn_wave_barrier();

                // v changed: discard speculation, recompute row cur+1's chain
                // (cN now holds row cur+2; reload cur+1 from LDS / same-XCD L2)
                if (hasnext) {
                    load_row(cur + 1, chop);
                    #pragma unroll
                    for (int k = 0; k < K16; ++k) r_nx[k] = (double)chop[k] - v_r[k];
                    lexmin(r_nx, mv_n, jm_n);
                }
            }

            // rotate pipeline state
            if (hasnext) {
                #pragma unroll
                for (int k = 0; k < K16; ++k) r_cur[k] = r_nx[k];
                minv = mv_n; jm = jm_n;
            }
        }
    }

    __syncthreads();   // waves 1-3 park here; wave 0 arrives after matching
    for (int j = t; j < Q_; j += T_) {
        const int rc = row4col_[j];
        out_ind [(b << 10) + j] = (rc >= 0) ? (float)rc : 0.0f;
        out_mask[(b << 10) + j] = (rc >= 0) ? 1.0f : 0.0f;
    }
}

extern "C" void kernel_launch(void* const* d_in, const int* in_sizes, int n_in,
                              void* d_out, int out_size, void* d_ws, size_t ws_size,
                              hipStream_t stream)
{
    const float* obj = (const float*)d_in[1];
    const float* cd  = (const float*)d_in[2];
    const float* gi  = (const float*)d_in[3];
    const int*   ngt = (const int*)d_in[4];
    float* out0 = (float*)d_out;
    float* out1 = out0 + B_ * Q_;

    const size_t need = (size_t)B_ * (G_ - LROWS) * Q_ * sizeof(float);  // 4 MB
    if (ws_size >= need) {
        matcher_fused<true><<<B_, T_, 0, stream>>>(obj, cd, gi, ngt,
                                                   (float*)d_ws, out0, out1);
    } else {
        matcher_fused<false><<<B_, T_, 0, stream>>>(obj, cd, gi, ngt,
                                                    nullptr, out0, out1);
    }
}

// Round 11
// 200.254 us; speedup vs baseline: 1.0767x; 1.0767x over previous
//
#include <hip/hip_runtime.h>
#include <math.h>

#define B_ 32
#define Q_ 1024
#define G_ 64
#define T_ 256    // build threads (4 waves); matcher runs on wave 0 only
#define K16 16    // columns per lane in matcher (Q_ / 64)
#define LROWS 32  // cost rows resident in LDS

// ---- cross-lane helpers -------------------------------------------------
template<int CTRL>
__device__ __forceinline__ double dpp_f64(double x) {
    union { double d; int i[2]; } a; a.d = x;
    union { int i[2]; double d; } r;
    r.i[0] = __builtin_amdgcn_update_dpp(a.i[0], a.i[0], CTRL, 0xF, 0xF, false);
    r.i[1] = __builtin_amdgcn_update_dpp(a.i[1], a.i[1], CTRL, 0xF, 0xF, false);
    return r.d;
}
#define ROR1 0x121
#define ROR2 0x122
#define ROR4 0x124
#define ROR8 0x128
#define BC15 0x142   // row_bcast15: row r's lane15 -> row r+1
#define BC31 0x143   // row_bcast31: lane31 -> rows 2,3

__device__ __forceinline__ double readlane_f64(double x, int sl) {
    const int s = __builtin_amdgcn_readfirstlane(sl);
    union { double d; int i2[2]; } a; a.d = x;
    union { int i2[2]; double d; } r;
    r.i2[0] = __builtin_amdgcn_readlane(a.i2[0], s);
    r.i2[1] = __builtin_amdgcn_readlane(a.i2[1], s);
    return r.d;
}
__device__ __forceinline__ int readlane_i32(int x, int sl) {
    return __builtin_amdgcn_readlane(x, __builtin_amdgcn_readfirstlane(sl));
}
// uniform-index select from a 16-entry register array
__device__ __forceinline__ int sel16(const int* p, int s) {
    int v = p[0];
    #pragma unroll
    for (int k = 1; k < K16; ++k) v = (s == k) ? p[k] : v;
    return v;
}

// Fused: 256-thread cost build (rows<32 -> LDS; rows>=32 -> same-XCD ctg),
// then SINGLE-WAVE Jonker-Volgenant with 1-step fast path (u[cur]==0 at row
// start; 1-step rows leave v unchanged => O(1) bookkeeping).
// Argmin: value = fmin tree + DPP ror1/2/4/8 + row_bcast15/31 + readlane(63);
// index = 16x ballot(cand==gv) + scalar smallest-k/ctz chain. Ties -> smallest
// j (k-major, lane-minor), exactly np.argmin first-occurrence.
template<bool HASWS>
__global__ __launch_bounds__(256) void matcher_fused(
    const float* __restrict__ obj, const float* __restrict__ cd,
    const float* __restrict__ gi, const int* __restrict__ ngt,
    float* __restrict__ ctg, float* __restrict__ out_ind,
    float* __restrict__ out_mask)
{
    __shared__ float ldsct[LROWS * 1025];            // 2-way bank alias: free
    __shared__ int   row4col_[Q_];                   // hops + final output
    __shared__ __align__(16) char scratch_[LROWS * 65 * 4]; // tile (build) / sh dump

    float (*tile)[65] = (float (*)[65])scratch_;
    double* sh_lds    = (double*)scratch_;

    const int b = blockIdx.x;
    const int t = threadIdx.x;
    const int l = t & 63;
    const int w = t >> 6;
    const int g = ngt[b];

    const float* objb = obj + (b << 10);
    const float* cdb  = cd + ((size_t)b << 16);
    const float* gib  = gi + ((size_t)b << 16);
    float* ctgb = HASWS ? (ctg + ((size_t)b << 15)) : (float*)nullptr;

    for (int j = t; j < Q_; j += T_) row4col_[j] = -1;

    // ---- build: all 256 threads; rows<32 direct to LDS, rows>=32 via tile ----
    if (g > 0) {
        const float4* cd4 = (const float4*)cdb;
        const float4* gi4 = (const float4*)gib;
        for (int jb = 0; jb < Q_; jb += 64) {
            #pragma unroll
            for (int p = 0; p < 4; ++p) {
                const int f  = t + (p << 8);
                const int jj = f >> 4;          // 0..63
                const int q  = f & 15;          // i-quad
                const int i0 = q << 2;          // 0,4,..,60
                const int j  = jb + jj;
                const float om = __fmul_rn(5.0f, -objb[j]);
                const float4 c4 = cd4[(j << 4) + q];
                const float4 q4 = gi4[(j << 4) + q];
                const float r0 = __fadd_rn(__fadd_rn(om, __fmul_rn(10.0f, c4.x)), __fmul_rn(2.0f, -q4.x));
                const float r1 = __fadd_rn(__fadd_rn(om, __fmul_rn(10.0f, c4.y)), __fmul_rn(2.0f, -q4.y));
                const float r2 = __fadd_rn(__fadd_rn(om, __fmul_rn(10.0f, c4.z)), __fmul_rn(2.0f, -q4.z));
                const float r3 = __fadd_rn(__fadd_rn(om, __fmul_rn(10.0f, c4.w)), __fmul_rn(2.0f, -q4.w));
                if (i0 < LROWS) {
                    ldsct[(i0 + 0) * 1025 + j] = r0;
                    ldsct[(i0 + 1) * 1025 + j] = r1;
                    ldsct[(i0 + 2) * 1025 + j] = r2;
                    ldsct[(i0 + 3) * 1025 + j] = r3;
                } else if (HASWS) {
                    tile[i0 - LROWS + 0][jj] = r0;
                    tile[i0 - LROWS + 1][jj] = r1;
                    tile[i0 - LROWS + 2][jj] = r2;
                    tile[i0 - LROWS + 3][jj] = r3;
                }
            }
            __syncthreads();
            if (HASWS) {
                #pragma unroll
                for (int r = 0; r < 8; ++r) {   // 32 rows x 64 cols / 256 thr
                    const int idx = (r << 8) + t;
                    const int i2 = idx >> 6, j2 = idx & 63;
                    if (LROWS + i2 < g)
                        ctgb[(i2 << 10) + jb + j2] = tile[i2][j2];   // coalesced
                }
            }
            __syncthreads();
        }
    }

    // ---- matcher: wave 0 only, zero barriers in the hot loop ----
    if (w == 0 && g > 0) {
        float objm[K16];
        if (!HASWS) {
            #pragma unroll
            for (int k = 0; k < K16; ++k) objm[k] = __fmul_rn(5.0f, -objb[l + (k << 6)]);
        }
        auto load_row = [&](int i, float* c) {
            if (i < LROWS) {
                #pragma unroll
                for (int k = 0; k < K16; ++k) c[k] = ldsct[i * 1025 + l + (k << 6)];
            } else if (HASWS) {
                #pragma unroll
                for (int k = 0; k < K16; ++k) c[k] = ctgb[((i - LROWS) << 10) + l + (k << 6)];
            } else {
                #pragma unroll
                for (int k = 0; k < K16; ++k) {
                    const int j = l + (k << 6);
                    const int idx = (j << 6) + i;
                    c[k] = __fadd_rn(__fadd_rn(objm[k], __fmul_rn(10.0f, cdb[idx])),
                                     __fmul_rn(2.0f, -gib[idx]));
                }
            }
        };
        // argmin over cand[16] x 64 lanes.
        auto lexmin = [&](const double* cand, double& gv_o, int& jm_o) {
            double t8[8];
            #pragma unroll
            for (int m = 0; m < 8; ++m) t8[m] = fmin(cand[2 * m], cand[2 * m + 1]);
            const double a4 = fmin(fmin(t8[0], t8[1]), fmin(t8[2], t8[3]));
            const double b4 = fmin(fmin(t8[4], t8[5]), fmin(t8[6], t8[7]));
            double bv = fmin(a4, b4);
            bv = fmin(bv, dpp_f64<ROR1>(bv));
            bv = fmin(bv, dpp_f64<ROR2>(bv));
            bv = fmin(bv, dpp_f64<ROR4>(bv));
            bv = fmin(bv, dpp_f64<ROR8>(bv));     // each 16-row: row min in all lanes
            bv = fmin(bv, dpp_f64<BC15>(bv));     // row1 |= row0, row2 |= row1, row3 |= row2
            bv = fmin(bv, dpp_f64<BC31>(bv));     // rows 2,3 |= min(row0,row1)
            const double gv = readlane_f64(bv, 63);   // lane63 = global min
            unsigned long long mk[K16];
            #pragma unroll
            for (int k = 0; k < K16; ++k) mk[k] = __ballot(cand[k] == gv);
            int jm = 0;
            #pragma unroll
            for (int k = K16 - 1; k >= 0; --k)
                if (mk[k]) jm = (k << 6) | (int)__builtin_ctzll(mk[k]);
            gv_o = gv; jm_o = jm;    // smallest k with a hit, lowest lane within
        };

        const double INF = __builtin_inf();
        double u_rep   = 0.0;     // u[l]
        int    c4r_rep = -1;      // col4row[l]
        unsigned asg   = 0u;      // bit k: column l+64k assigned
        double v_r[K16], sh_r[K16];
        int    path_r[K16];
        float  c_row[K16], c_next[K16];
        #pragma unroll
        for (int k = 0; k < K16; ++k) { v_r[k] = 0.0; path_r[k] = 0; }

        load_row(0, c_next);

        for (int cur = 0; cur < g; ++cur) {
            #pragma unroll
            for (int k = 0; k < K16; ++k) c_row[k] = c_next[k];
            if (cur + 1 < g) load_row(cur + 1, c_next);   // hides behind whole row

            // ---- fast first step: u[cur]=0, minv=0 -> r = (f64)c - v ----
            double r[K16];
            #pragma unroll
            for (int k = 0; k < K16; ++k) r[k] = (double)c_row[k] - v_r[k];
            double minv; int jm;
            lexmin(r, minv, jm);
            const int owner0 = jm & 63, slot0 = jm >> 6;
            const unsigned oa0 = (unsigned)readlane_i32((int)asg, owner0);

            if (!((oa0 >> slot0) & 1u)) {
                // ---- 1-step row: O(1) state update (v provably unchanged) ----
                if (l == cur)    { u_rep += minv; c4r_rep = jm; }
                if (l == owner0) asg |= 1u << slot0;
                if (l == 0)      row4col_[jm] = cur;
            } else {
                // ---- slow path: materialize step-1 state, standard Dijkstra ----
                unsigned sc = 0u;
                #pragma unroll
                for (int k = 0; k < K16; ++k) { sh_r[k] = r[k]; path_r[k] = cur; }
                if (l == owner0) sc |= 1u << slot0;
                int i = row4col_[jm];
                bool inSR = (l == cur) || (l == i);
                double ui = readlane_f64(u_rep, i);
                load_row(i, c_row);
                int sink = -1;

                while (sink < 0) {
                    double cand[K16];
                    #pragma unroll
                    for (int k = 0; k < K16; ++k) {
                        const double rr = ((minv + (double)c_row[k]) - ui) - v_r[k];
                        const bool notSC = !((sc >> k) & 1u);
                        const bool upd = notSC && (rr < sh_r[k]);   // strict <
                        sh_r[k]   = upd ? rr : sh_r[k];
                        path_r[k] = upd ? i : path_r[k];
                        cand[k] = notSC ? sh_r[k] : INF;
                    }
                    lexmin(cand, minv, jm);
                    if (l == (jm & 63)) sc |= 1u << (jm >> 6);
                    const unsigned oa = (unsigned)readlane_i32((int)asg, jm & 63);
                    if (!((oa >> (jm >> 6)) & 1u)) {
                        sink = jm;
                    } else {
                        i = row4col_[jm];
                        if (l == i) inSR = true;
                        ui = readlane_f64(u_rep, i);
                        load_row(i, c_row);
                    }
                }

                // dual updates (reference order: u, then v, then augment)
                if (l == cur) u_rep += minv;
                #pragma unroll
                for (int k = 0; k < K16; ++k) sh_lds[l + (k << 6)] = sh_r[k];
                __builtin_amdgcn_wave_barrier();
                if (inSR && l != cur) u_rep += minv - sh_lds[c4r_rep];
                __builtin_amdgcn_wave_barrier();
                #pragma unroll
                for (int k = 0; k < K16; ++k) {
                    const double nv = v_r[k] - (minv - sh_r[k]);
                    v_r[k] = ((sc >> k) & 1u) ? nv : v_r[k];
                }

                // augment along alternating path
                int j = sink;
                while (true) {
                    const int so = j & 63, ss = j >> 6;
                    const int ii = readlane_i32(sel16(path_r, ss), so);
                    const int nj = readlane_i32(c4r_rep, ii);   // old col4row[ii]
                    if (l == 0) row4col_[j] = ii;
                    if (l == so) asg |= 1u << ss;
                    if (l == ii) c4r_rep = j;
                    j = nj;
                    if (ii == cur) break;
                }
                __builtin_amdgcn_wave_barrier();

                // c_row was clobbered by hop loads; c_next still holds row cur+1
            }
        }
    }

    __syncthreads();   // waves 1-3 park here; wave 0 arrives after matching
    for (int j = t; j < Q_; j += T_) {
        const int rc = row4col_[j];
        out_ind [(b << 10) + j] = (rc >= 0) ? (float)rc : 0.0f;
        out_mask[(b << 10) + j] = (rc >= 0) ? 1.0f : 0.0f;
    }
}

extern "C" void kernel_launch(void* const* d_in, const int* in_sizes, int n_in,
                              void* d_out, int out_size, void* d_ws, size_t ws_size,
                              hipStream_t stream)
{
    const float* obj = (const float*)d_in[1];
    const float* cd  = (const float*)d_in[2];
    const float* gi  = (const float*)d_in[3];
    const int*   ngt = (const int*)d_in[4];
    float* out0 = (float*)d_out;
    float* out1 = out0 + B_ * Q_;

    const size_t need = (size_t)B_ * (G_ - LROWS) * Q_ * sizeof(float);  // 4 MB
    if (ws_size >= need) {
        matcher_fused<true><<<B_, T_, 0, stream>>>(obj, cd, gi, ngt,
                                                   (float*)d_ws, out0, out1);
    } else {
        matcher_fused<false><<<B_, T_, 0, stream>>>(obj, cd, gi, ngt,
                                                    nullptr, out0, out1);
    }
}